// Round 14
// baseline (283.255 us; speedup 1.0000x reference)
//
#include <hip/hip_runtime.h>
#include <math.h>

#define NNODES 20000
#define NEDGES 320000
#define RREL 8
#define EPSBN 1e-5f

typedef float f32x4 __attribute__((ext_vector_type(4)));
typedef __bf16 bf16x8 __attribute__((ext_vector_type(8)));
typedef unsigned short u16x8 __attribute__((ext_vector_type(8)));

static __device__ __forceinline__ unsigned short f2bf(float f) {
    unsigned int x = __builtin_bit_cast(unsigned int, f);
    unsigned int r = x + 0x7FFFu + ((x >> 16) & 1u);
    return (unsigned short)(r >> 16);
}
static __device__ __forceinline__ float bf2f(unsigned short u) {
    unsigned int x = ((unsigned int)u) << 16;
    return __builtin_bit_cast(float, x);
}

// ---------------- CSR build (sorted by (dst, rel)) ----------------
__global__ __launch_bounds__(256) void k_count(const int* __restrict__ dst, const int* __restrict__ et,
                                               int* __restrict__ cnt) {
    int e = blockIdx.x * 256 + threadIdx.x;
    if (e >= NEDGES) return;
    atomicAdd(&cnt[dst[e] * RREL + et[e]], 1);
}

__global__ __launch_bounds__(256) void k_deg(const int* __restrict__ cnt, int* __restrict__ deg) {
    int i = blockIdx.x * 256 + threadIdx.x;
    if (i >= NNODES) return;
    const int4* p = (const int4*)(cnt + i * 8);
    int4 a = p[0], b = p[1];
    deg[i] = a.x + a.y + a.z + a.w + b.x + b.y + b.z + b.w;
}

__global__ __launch_bounds__(256) void k_scan(const int* __restrict__ deg, int* __restrict__ start) {
    __shared__ int part[256];
    int t = threadIdx.x;
    int i0 = t * 80;
    int s = 0;
    if (i0 < NNODES) {
        for (int i = 0; i < 80; i += 4) {
            int4 v = *(const int4*)(deg + i0 + i);
            s += v.x + v.y + v.z + v.w;
        }
    }
    part[t] = s;
    __syncthreads();
    if (t == 0) {
        int acc = 0;
        for (int j = 0; j < 256; j++) { int v = part[j]; part[j] = acc; acc += v; }
    }
    __syncthreads();
    int acc = part[t];
    if (i0 < NNODES) {
        for (int i = 0; i < 80; i += 4) {
            int4 v = *(const int4*)(deg + i0 + i);
            int4 st;
            st.x = acc; acc += v.x;
            st.y = acc; acc += v.y;
            st.z = acc; acc += v.z;
            st.w = acc; acc += v.w;
            *(int4*)(start + i0 + i) = st;
        }
    }
}

__global__ __launch_bounds__(256) void k_sub(const int* __restrict__ cnt, const int* __restrict__ start,
                                             int* __restrict__ start2, int* __restrict__ cursor2) {
    int i = blockIdx.x * 256 + threadIdx.x;
    if (i >= NNODES) return;
    const int4* p = (const int4*)(cnt + i * 8);
    int4 a = p[0], b = p[1];
    int acc = start[i];
    int s2[8];
    s2[0] = acc; acc += a.x;
    s2[1] = acc; acc += a.y;
    s2[2] = acc; acc += a.z;
    s2[3] = acc; acc += a.w;
    s2[4] = acc; acc += b.x;
    s2[5] = acc; acc += b.y;
    s2[6] = acc; acc += b.z;
    s2[7] = acc;
    ((int4*)(start2 + i * 8))[0] = make_int4(s2[0], s2[1], s2[2], s2[3]);
    ((int4*)(start2 + i * 8))[1] = make_int4(s2[4], s2[5], s2[6], s2[7]);
    ((int4*)(cursor2 + i * 8))[0] = make_int4(s2[0], s2[1], s2[2], s2[3]);
    ((int4*)(cursor2 + i * 8))[1] = make_int4(s2[4], s2[5], s2[6], s2[7]);
}

__global__ __launch_bounds__(256) void k_fill(const int* __restrict__ src, const int* __restrict__ dst,
                                              const int* __restrict__ et, int* __restrict__ cursor2,
                                              int* __restrict__ csr) {
    int e = blockIdx.x * 256 + threadIdx.x;
    if (e >= NEDGES) return;
    int pos = atomicAdd(&cursor2[dst[e] * RREL + et[e]], 1);
    csr[pos] = src[e];
}

// ---------------- fused prep: x->bf16 + fragment-major B' layouts ----------------
#define PR0 (NNODES * 32)
#define PR1 (2048 * 256)
#define PR2 (256 * 256)
#define PR3 (1024 * 256)
__global__ __launch_bounds__(256) void k_prep(const float* __restrict__ x, const float* __restrict__ Wrel,
                                              const float* __restrict__ Wroot,
                                              const float* __restrict__ Wq, const float* __restrict__ Wk,
                                              const float* __restrict__ Wv, const float* __restrict__ Ws,
                                              const float* __restrict__ bq, const float* __restrict__ bk,
                                              const float* __restrict__ bv, const float* __restrict__ bs,
                                              unsigned short* __restrict__ xb, unsigned short* __restrict__ BtAp,
                                              unsigned short* __restrict__ B2p, float* __restrict__ bias2) {
    int i = blockIdx.x * 256 + threadIdx.x;
    if (i < PR0) {
        const float4* p = (const float4*)(x + (size_t)i * 8);
        float4 v0 = p[0], v1 = p[1];
        u16x8 w;
        w[0] = f2bf(v0.x); w[1] = f2bf(v0.y); w[2] = f2bf(v0.z); w[3] = f2bf(v0.w);
        w[4] = f2bf(v1.x); w[5] = f2bf(v1.y); w[6] = f2bf(v1.z); w[7] = f2bf(v1.w);
        *(u16x8*)(xb + (size_t)i * 8) = w;
    } else if (i < PR0 + PR1) {
        int idx = i - PR0;
        int e = idx & 7, ln = (idx >> 3) & 63, f = (idx >> 9) & 3, w = (idx >> 11) & 3, ks = idx >> 13;
        int h = w * 64 + f * 16 + (ln & 15);
        int k = ks * 32 + ((ln >> 4) << 3) + e;
        int r = k >> 8, g = k & 255;
        BtAp[idx] = f2bf(Wrel[(size_t)r * 65536 + (size_t)g * 256 + h]);
    } else if (i < PR0 + PR1 + PR2) {
        int idx = i - PR0 - PR1;
        int e = idx & 7, ln = (idx >> 3) & 63, f = (idx >> 9) & 3, w = (idx >> 11) & 3, ks2 = idx >> 13;
        int h = w * 64 + f * 16 + (ln & 15);
        int kk = ks2 * 32 + ((ln >> 4) << 3) + e;
        BtAp[PR1 + idx] = f2bf(Wroot[(size_t)kk * 256 + h]);
    } else {
        int idx = i - PR0 - PR1 - PR2;
        int e = idx & 7, ln = (idx >> 3) & 63, f = (idx >> 9) & 3, w = (idx >> 11) & 3;
        int ks = (idx >> 13) & 7, ct = idx >> 16;
        int c = ct * 256 + w * 64 + f * 16 + (ln & 15);
        int g = ks * 32 + ((ln >> 4) << 3) + e;
        const float* W = (c < 256) ? Wq : (c < 512) ? Wk : (c < 768) ? Wv : Ws;
        int cc = c & 255;
        B2p[idx] = f2bf(W[(size_t)g * 256 + cc]);
        if (ks == 0 && e == 0 && (ln >> 4) == 0) {
            const float* B = (c < 256) ? bq : (c < 512) ? bk : (c < 768) ? bv : bs;
            bias2[c] = B[cc];
        }
    }
}

// ---------------- mean-gather v2: one wave per (node, rel); S[N][2048] means only ----------------
__global__ __launch_bounds__(256) void k_mean(const unsigned short* __restrict__ xb, const int* __restrict__ csr,
                                              const int* __restrict__ start2, const int* __restrict__ cnt,
                                              unsigned short* __restrict__ S) {
    int pid = blockIdx.x * 4 + (threadIdx.x >> 6);
    int lane = threadIdx.x & 63;
    if (pid >= NNODES * 8) return;
    int s0 = start2[pid], n = cnt[pid];
    float4 acc = make_float4(0.f, 0.f, 0.f, 0.f);
    int j = 0;
    for (; j + 4 <= n; j += 4) {
        int sa = csr[s0 + j], sb = csr[s0 + j + 1], sc2 = csr[s0 + j + 2], sd = csr[s0 + j + 3];
        ushort4 ya = *(const ushort4*)(xb + (size_t)sa * 256 + lane * 4);
        ushort4 yb = *(const ushort4*)(xb + (size_t)sb * 256 + lane * 4);
        ushort4 yc = *(const ushort4*)(xb + (size_t)sc2 * 256 + lane * 4);
        ushort4 yd = *(const ushort4*)(xb + (size_t)sd * 256 + lane * 4);
        acc.x += bf2f(ya.x) + bf2f(yb.x) + bf2f(yc.x) + bf2f(yd.x);
        acc.y += bf2f(ya.y) + bf2f(yb.y) + bf2f(yc.y) + bf2f(yd.y);
        acc.z += bf2f(ya.z) + bf2f(yb.z) + bf2f(yc.z) + bf2f(yd.z);
        acc.w += bf2f(ya.w) + bf2f(yb.w) + bf2f(yc.w) + bf2f(yd.w);
    }
    for (; j < n; j++) {
        int sa = csr[s0 + j];
        ushort4 ya = *(const ushort4*)(xb + (size_t)sa * 256 + lane * 4);
        acc.x += bf2f(ya.x);
        acc.y += bf2f(ya.y);
        acc.z += bf2f(ya.z);
        acc.w += bf2f(ya.w);
    }
    float sc = 1.0f / (float)(n > 0 ? n : 1);
    ushort4 o;
    o.x = f2bf(acc.x * sc); o.y = f2bf(acc.y * sc);
    o.z = f2bf(acc.z * sc); o.w = f2bf(acc.w * sc);
    *(ushort4*)(S + (size_t)(pid >> 3) * 2048 + (pid & 7) * 256 + lane * 4) = o;
}

// ---------------- GEMM v10: 32x256 tile, B from L2 (fragment-major), 2-deep prefetch rings ----------------
// MODE 5: A = [S (ks<64, stride 2048) | x_bf (ks>=64, stride 256)]; bf16 out = acc + bias (NC=256)
// MODE 3: single A (stride K); ct<3 -> bf16 QKV + bias (NC=768); ct==3 -> f32 skip C2 + bias
template<int MODE>
__global__ __launch_bounds__(256) void k_gemm10(const unsigned short* __restrict__ A,
                                                const unsigned short* __restrict__ A2,
                                                const unsigned short* __restrict__ Bp,
                                                const float* __restrict__ bias,
                                                unsigned short* __restrict__ C, float* __restrict__ C2,
                                                int M, int K, int nks, int nct, int q, int rr) {
    __shared__ __align__(16) unsigned short SH[8448];   // A dbuf 2x2KB; epilogue bounce [32][264]

    int bid = blockIdx.x;
    int xcd = bid & 7, idx = bid >> 3;
    int base = (xcd < rr) ? xcd * (q + 1) : rr * (q + 1) + (xcd - rr) * q;
    int nid = base + idx;
    int rowT = nid / nct, ct = nid - rowT * nct;
    int brow = rowT * 32;

    int tid = threadIdx.x;
    int lane = tid & 63, w = tid >> 6;
    int lr = lane & 15, lq = lane >> 4;

    bool astage = tid < 128;
    int arow = (tid >> 2) & 31, ac = tid & 3;
    int grow = brow + arow;
    const unsigned short* gS = (MODE == 5) ? (A + (size_t)grow * 2048 + ac * 8)
                                           : (A + (size_t)grow * K + ac * 8);
    const unsigned short* gX = (MODE == 5) ? (A2 + (size_t)grow * 256 + ac * 8) : nullptr;
    bool aok = astage && grow < M;
    int awoff = arow * 32 + ac * 8;
    const u16x8 zz = {0, 0, 0, 0, 0, 0, 0, 0};

    const unsigned short* gB = Bp + ((size_t)ct * nks) * 8192 + ((size_t)(w * 4) * 64 + lane) * 8;

    // A address helper (wave-uniform ks branch)
    auto aLoad = [&](int kss) -> u16x8 {
        if (!aok) return zz;
        if (MODE == 5) {
            return (kss < 64) ? *(const u16x8*)(gS + (size_t)kss * 32)
                              : *(const u16x8*)(gX + (size_t)(kss - 64) * 32);
        }
        return *(const u16x8*)(gS + (size_t)kss * 32);
    };

    u16x8 raA = aLoad(0);
    u16x8 raB = (nks > 1) ? aLoad(1) : zz;
    u16x8 rb0[4], rb1[4];
    #pragma unroll
    for (int f = 0; f < 4; f++) rb0[f] = *(const u16x8*)(gB + f * 512);
    #pragma unroll
    for (int f = 0; f < 4; f++) rb1[f] = (nks > 1) ? *(const u16x8*)(gB + 8192 + f * 512) : zz;

    f32x4 acc[2][4];
    #pragma unroll
    for (int i = 0; i < 2; i++)
        #pragma unroll
        for (int j = 0; j < 4; j++) acc[i][j] = (f32x4){0.f, 0.f, 0.f, 0.f};

    int cur = 0;
    for (int ks = 0; ks < nks; ks++) {
        if (astage) *(u16x8*)(SH + cur * 1024 + awoff) = raA;
        __syncthreads();
        raA = raB;
        u16x8 rbu[4];
        #pragma unroll
        for (int f = 0; f < 4; f++) { rbu[f] = rb0[f]; rb0[f] = rb1[f]; }
        if (ks + 2 < nks) {
            raB = aLoad(ks + 2);
            #pragma unroll
            for (int f = 0; f < 4; f++)
                rb1[f] = *(const u16x8*)(gB + (size_t)(ks + 2) * 8192 + f * 512);
        }
        bf16x8 af[2];
        #pragma unroll
        for (int i = 0; i < 2; i++)
            af[i] = *(const bf16x8*)(SH + cur * 1024 + (i * 16 + lr) * 32 + lq * 8);
        #pragma unroll
        for (int i = 0; i < 2; i++)
            #pragma unroll
            for (int j = 0; j < 4; j++)
                acc[i][j] = __builtin_amdgcn_mfma_f32_16x16x32_bf16(af[i], (bf16x8)rbu[j], acc[i][j], 0, 0, 0);
        cur ^= 1;
    }

    __syncthreads();

    bool f32out = (MODE == 3) && (ct == 3);
    if (!f32out) {
        float bb[4];
        #pragma unroll
        for (int j = 0; j < 4; j++)
            bb[j] = bias[((MODE == 5) ? 0 : ct * 256) + w * 64 + j * 16 + lr];
        #pragma unroll
        for (int i = 0; i < 2; i++)
            #pragma unroll
            for (int j = 0; j < 4; j++)
                #pragma unroll
                for (int r = 0; r < 4; r++) {
                    int lrow = i * 16 + lq * 4 + r;
                    int col = w * 64 + j * 16 + lr;
                    SH[lrow * 264 + col] = f2bf(acc[i][j][r] + bb[j]);
                }
        __syncthreads();
        int row = tid >> 3;
        int ch = (tid & 7) * 32;
        int gr2 = brow + row;
        if (gr2 < M) {
            unsigned short* dstp = (MODE == 5) ? (C + (size_t)gr2 * 256 + ch)
                                               : (C + (size_t)gr2 * 768 + ct * 256 + ch);
            const unsigned short* srcp = SH + row * 264 + ch;
            #pragma unroll
            for (int k = 0; k < 4; k++)
                *(u16x8*)(dstp + k * 8) = *(const u16x8*)(srcp + k * 8);
        }
    } else {
        #pragma unroll
        for (int i = 0; i < 2; i++)
            #pragma unroll
            for (int j = 0; j < 4; j++) {
                int col = w * 64 + j * 16 + lr;
                float bv2 = bias[768 + col];
                #pragma unroll
                for (int r = 0; r < 4; r++) {
                    int gr = brow + i * 16 + lq * 4 + r;
                    if (gr < M) C2[(size_t)gr * 256 + col] = acc[i][j][r] + bv2;
                }
            }
    }
}

// ---------------- fused attention v2: TWO waves per node (split edges) + LDS flash-merge ----------------
__global__ __launch_bounds__(256) void k_attn(const unsigned short* __restrict__ QKV, const int* __restrict__ csr,
                                              const int* __restrict__ start2, const int* __restrict__ deg,
                                              float* __restrict__ out) {
    __shared__ float LM[2], LD[2];
    __shared__ float LACC[2][256];
    int tid = threadIdx.x;
    int pn = tid >> 7;               // node slot in block (0..1)
    int half = (tid >> 6) & 1;       // edge-half handled by this wave
    int lane = tid & 63;
    int node = blockIdx.x * 2 + pn;  // grid == NNODES/2 exactly
    int s0 = start2[node * 8];
    int n = deg[node];
    ushort4 qu = *(const ushort4*)(QKV + (size_t)node * 768 + lane * 4);
    float q0 = bf2f(qu.x), q1 = bf2f(qu.y), q2 = bf2f(qu.z), q3 = bf2f(qu.w);
    float m = -INFINITY, den = 0.f;
    float4 acc = make_float4(0.f, 0.f, 0.f, 0.f);
    int nh = (n + 1) >> 1;
    int jb = half * nh;
    int je = jb + nh; if (je > n) je = n;
    int j = jb;
    for (; j + 8 <= je; j += 8) {
        int sidx[8];
        #pragma unroll
        for (int t = 0; t < 8; t++) sidx[t] = csr[s0 + j + t];
        ushort4 kk[8], vv[8];
        #pragma unroll
        for (int t = 0; t < 8; t++) {
            const unsigned short* bp = QKV + (size_t)sidx[t] * 768;
            kk[t] = *(const ushort4*)(bp + 256 + lane * 4);
            vv[t] = *(const ushort4*)(bp + 512 + lane * 4);
        }
        float p[8];
        #pragma unroll
        for (int t = 0; t < 8; t++)
            p[t] = q0 * bf2f(kk[t].x) + q1 * bf2f(kk[t].y) + q2 * bf2f(kk[t].z) + q3 * bf2f(kk[t].w);
        #pragma unroll
        for (int o = 32; o; o >>= 1) {
            #pragma unroll
            for (int t = 0; t < 8; t++) p[t] += __shfl_xor(p[t], o);
        }
        float pm = p[0];
        #pragma unroll
        for (int t = 1; t < 8; t++) pm = fmaxf(pm, p[t]);
        pm *= 0.0625f;
        if (pm > m) {
            float rr = __expf(m - pm);
            den *= rr;
            acc.x *= rr; acc.y *= rr; acc.z *= rr; acc.w *= rr;
            m = pm;
        }
        #pragma unroll
        for (int t = 0; t < 8; t++) {
            float e = __expf(p[t] * 0.0625f - m);
            den += e;
            acc.x += e * bf2f(vv[t].x);
            acc.y += e * bf2f(vv[t].y);
            acc.z += e * bf2f(vv[t].z);
            acc.w += e * bf2f(vv[t].w);
        }
    }
    for (; j < je; j++) {
        const unsigned short* basep = QKV + (size_t)csr[s0 + j] * 768;
        ushort4 ku = *(const ushort4*)(basep + 256 + lane * 4);
        ushort4 vu = *(const ushort4*)(basep + 512 + lane * 4);
        float p = q0 * bf2f(ku.x) + q1 * bf2f(ku.y) + q2 * bf2f(ku.z) + q3 * bf2f(ku.w);
        #pragma unroll
        for (int o = 32; o; o >>= 1) p += __shfl_xor(p, o);
        p *= 0.0625f;
        if (p > m) {
            float rr = __expf(m - p);
            den *= rr;
            acc.x *= rr; acc.y *= rr; acc.z *= rr; acc.w *= rr;
            m = p;
        }
        float ex = __expf(p - m);
        den += ex;
        acc.x += ex * bf2f(vu.x); acc.y += ex * bf2f(vu.y);
        acc.z += ex * bf2f(vu.z); acc.w += ex * bf2f(vu.w);
    }
    // merge partials: wave half==1 publishes, wave half==0 combines and writes
    if (half == 1) {
        if (lane == 0) { LM[pn] = m; LD[pn] = den; }
        *(float4*)&LACC[pn][lane * 4] = acc;
    }
    __syncthreads();
    if (half == 0 && n > 0) {
        float m1 = LM[pn], den1 = LD[pn];
        float4 a1 = *(const float4*)&LACC[pn][lane * 4];
        if (den1 > 0.f) {
            float M = fmaxf(m, m1);
            float f0 = __expf(m - M);
            float f1 = __expf(m1 - M);
            den = den * f0 + den1 * f1;
            acc.x = acc.x * f0 + a1.x * f1;
            acc.y = acc.y * f0 + a1.y * f1;
            acc.z = acc.z * f0 + a1.z * f1;
            acc.w = acc.w * f0 + a1.w * f1;
        }
        float rinv = 1.0f / fmaxf(den, 1e-16f);
        float4* o4 = (float4*)(out + (size_t)node * 256);
        float4 o = o4[lane];
        o.x += acc.x * rinv; o.y += acc.y * rinv; o.z += acc.z * rinv; o.w += acc.w * rinv;
        o4[lane] = o;
    }
}

// ---------------- batch norm + leaky relu ----------------
__global__ __launch_bounds__(256) void k_bnstats(const float* __restrict__ out, float* __restrict__ sums,
                                                 float* __restrict__ sumsq) {
    int c = threadIdx.x;
    int rows_per = (NNODES + gridDim.x - 1) / gridDim.x;
    int r0 = blockIdx.x * rows_per;
    int r1 = r0 + rows_per; if (r1 > NNODES) r1 = NNODES;
    float s = 0.f, ss = 0.f;
    for (int r = r0; r < r1; r++) {
        float v = out[(size_t)r * 256 + c];
        s += v; ss += v * v;
    }
    atomicAdd(&sums[c], s);
    atomicAdd(&sumsq[c], ss);
}

__global__ __launch_bounds__(256) void k_bnapply(float4* __restrict__ out, const float* __restrict__ sums,
                                                 const float* __restrict__ sumsq, const float* __restrict__ gamma,
                                                 const float* __restrict__ beta) {
    int i = blockIdx.x * 256 + threadIdx.x;
    if (i >= NNODES * 64) return;
    int c4 = i & 63;
    float4 sc, sh;
    #pragma unroll
    for (int t = 0; t < 4; t++) {
        int c = c4 * 4 + t;
        float mu = sums[c] * (1.0f / NNODES);
        float var = sumsq[c] * (1.0f / NNODES) - mu * mu;
        float s = gamma[c] * rsqrtf(fmaxf(var, 0.f) + EPSBN);
        ((float*)&sc)[t] = s;
        ((float*)&sh)[t] = beta[c] - mu * s;
    }
    float4 v = out[i];
    v.x = v.x * sc.x + sh.x; v.y = v.y * sc.y + sh.y;
    v.z = v.z * sc.z + sh.z; v.w = v.w * sc.w + sh.w;
    v.x = v.x > 0.f ? v.x : 0.01f * v.x;
    v.y = v.y > 0.f ? v.y : 0.01f * v.y;
    v.z = v.z > 0.f ? v.z : 0.01f * v.z;
    v.w = v.w > 0.f ? v.w : 0.01f * v.w;
    out[i] = v;
}

extern "C" void kernel_launch(void* const* d_in, const int* in_sizes, int n_in,
                              void* d_out, int out_size, void* d_ws, size_t ws_size,
                              hipStream_t stream) {
    const float* x = (const float*)d_in[0];
    const int* ei = (const int*)d_in[1];
    const int* etype = (const int*)d_in[2];
    const float* Wrel = (const float*)d_in[3];
    const float* Wroot = (const float*)d_in[4];
    const float* b1 = (const float*)d_in[5];
    const float* Wq = (const float*)d_in[6];
    const float* bq = (const float*)d_in[7];
    const float* Wk = (const float*)d_in[8];
    const float* bk = (const float*)d_in[9];
    const float* Wv = (const float*)d_in[10];
    const float* bv = (const float*)d_in[11];
    const float* Ws = (const float*)d_in[12];
    const float* bs = (const float*)d_in[13];
    const float* gamma = (const float*)d_in[14];
    const float* beta = (const float*)d_in[15];
    float* out = (float*)d_out;

    const int* srcA = ei;
    const int* dstA = ei + NEDGES;

    char* w = (char*)d_ws;
    unsigned short* S = (unsigned short*)w;     w += (size_t)NNODES * 2048 * 2;   // 81.9 MB (means only)
    unsigned short* x_bf = (unsigned short*)w;  w += (size_t)NNODES * 256 * 2;
    unsigned short* x1bf = (unsigned short*)w;  w += (size_t)NNODES * 256 * 2;
    unsigned short* QKVbf = (unsigned short*)w; w += (size_t)NNODES * 768 * 2;
    unsigned short* BtAp = (unsigned short*)w;  w += (size_t)256 * 2304 * 2;
    unsigned short* B2p = (unsigned short*)w;   w += (size_t)1024 * 256 * 2;
    float* bias2 = (float*)w;                   w += 1024 * 4;
    int* cnt = (int*)w;                         w += (size_t)NNODES * RREL * 4;
    int* deg = (int*)w;                         w += (size_t)NNODES * 4;
    int* startv = (int*)w;                      w += (size_t)NNODES * 4;
    int* start2 = (int*)w;                      w += (size_t)NNODES * RREL * 4;
    int* cursor2 = (int*)w;                     w += (size_t)NNODES * RREL * 4;
    int* csr = (int*)w;                         w += (size_t)NEDGES * 4;
    float* sums = (float*)w;                    w += 1024;
    float* sumsq = (float*)w;                   w += 1024;
    size_t need = (size_t)(w - (char*)d_ws);
    if (ws_size < need) return;

    hipMemsetAsync(cnt, 0, (size_t)NNODES * RREL * 4, stream);
    hipMemsetAsync(sums, 0, 2048, stream);

    k_count<<<(NEDGES + 255) / 256, 256, 0, stream>>>(dstA, etype, cnt);
    k_deg<<<(NNODES + 255) / 256, 256, 0, stream>>>(cnt, deg);
    k_scan<<<1, 256, 0, stream>>>(deg, startv);
    k_sub<<<(NNODES + 255) / 256, 256, 0, stream>>>(cnt, startv, start2, cursor2);
    k_fill<<<(NEDGES + 255) / 256, 256, 0, stream>>>(srcA, dstA, etype, cursor2, csr);

    k_prep<<<(PR0 + PR1 + PR2 + PR3) / 256, 256, 0, stream>>>(x, Wrel, Wroot, Wq, Wk, Wv, Ws,
                                                              bq, bk, bv, bs, x_bf, BtAp, B2p, bias2);

    // S[d][r*256..] = mean_r(x) (bf16); one wave per (node, rel)
    k_mean<<<(NNODES * 8 + 3) / 4, 256, 0, stream>>>(x_bf, csr, start2, cnt, S);

    // x1bf = bf16([S | x_bf] @ [W_0..W_7; W_root] + b1); 32x256 tiles, 625 blocks
    {
        int nwg = 625;
        int q = nwg / 8, rr = nwg % 8;
        k_gemm10<5><<<nwg, 256, 0, stream>>>(S, x_bf, BtAp, b1, x1bf, nullptr, NNODES, 2304, 72, 1, q, rr);
    }

    // [q|k|v -> QKVbf, skip -> out] = x1 @ [Wq|Wk|Wv|Wskip] + bias2; 32x256 tiles, 2500 blocks
    {
        int nwg = 625 * 4;
        int q = nwg / 8, rr = nwg % 8;
        k_gemm10<3><<<nwg, 256, 0, stream>>>(x1bf, nullptr, B2p, bias2, QKVbf, out, NNODES, 256, 8, 4, q, rr);
    }

    // fused attention: 2 waves per node + LDS merge
    k_attn<<<NNODES / 2, 256, 0, stream>>>(QKVbf, csr, start2, deg, out);

    k_bnstats<<<400, 256, 0, stream>>>(out, sums, sumsq);
    k_bnapply<<<(NNODES * 64 + 255) / 256, 256, 0, stream>>>((float4*)out, sums, sumsq, gamma, beta);
}

// Round 15
// 273.234 us; speedup vs baseline: 1.0367x; 1.0367x over previous
//
#include <hip/hip_runtime.h>
#include <math.h>

#define NNODES 20000
#define NEDGES 320000
#define RREL 8
#define EPSBN 1e-5f

typedef float f32x4 __attribute__((ext_vector_type(4)));
typedef __bf16 bf16x8 __attribute__((ext_vector_type(8)));
typedef unsigned short u16x8 __attribute__((ext_vector_type(8)));

static __device__ __forceinline__ unsigned short f2bf(float f) {
    unsigned int x = __builtin_bit_cast(unsigned int, f);
    unsigned int r = x + 0x7FFFu + ((x >> 16) & 1u);
    return (unsigned short)(r >> 16);
}
static __device__ __forceinline__ float bf2f(unsigned short u) {
    unsigned int x = ((unsigned int)u) << 16;
    return __builtin_bit_cast(float, x);
}

// ---------------- CSR build (sorted by (dst, rel)) ----------------
__global__ __launch_bounds__(256) void k_count(const int* __restrict__ dst, const int* __restrict__ et,
                                               int* __restrict__ cnt) {
    int e = blockIdx.x * 256 + threadIdx.x;
    if (e >= NEDGES) return;
    atomicAdd(&cnt[dst[e] * RREL + et[e]], 1);
}

__global__ __launch_bounds__(256) void k_deg(const int* __restrict__ cnt, int* __restrict__ deg) {
    int i = blockIdx.x * 256 + threadIdx.x;
    if (i >= NNODES) return;
    const int4* p = (const int4*)(cnt + i * 8);
    int4 a = p[0], b = p[1];
    deg[i] = a.x + a.y + a.z + a.w + b.x + b.y + b.z + b.w;
}

__global__ __launch_bounds__(256) void k_scan(const int* __restrict__ deg, int* __restrict__ start) {
    __shared__ int part[256];
    int t = threadIdx.x;
    int i0 = t * 80;
    int s = 0;
    if (i0 < NNODES) {
        for (int i = 0; i < 80; i += 4) {
            int4 v = *(const int4*)(deg + i0 + i);
            s += v.x + v.y + v.z + v.w;
        }
    }
    part[t] = s;
    __syncthreads();
    if (t == 0) {
        int acc = 0;
        for (int j = 0; j < 256; j++) { int v = part[j]; part[j] = acc; acc += v; }
    }
    __syncthreads();
    int acc = part[t];
    if (i0 < NNODES) {
        for (int i = 0; i < 80; i += 4) {
            int4 v = *(const int4*)(deg + i0 + i);
            int4 st;
            st.x = acc; acc += v.x;
            st.y = acc; acc += v.y;
            st.z = acc; acc += v.z;
            st.w = acc; acc += v.w;
            *(int4*)(start + i0 + i) = st;
        }
    }
}

__global__ __launch_bounds__(256) void k_sub(const int* __restrict__ cnt, const int* __restrict__ start,
                                             int* __restrict__ start2, int* __restrict__ cursor2) {
    int i = blockIdx.x * 256 + threadIdx.x;
    if (i >= NNODES) return;
    const int4* p = (const int4*)(cnt + i * 8);
    int4 a = p[0], b = p[1];
    int acc = start[i];
    int s2[8];
    s2[0] = acc; acc += a.x;
    s2[1] = acc; acc += a.y;
    s2[2] = acc; acc += a.z;
    s2[3] = acc; acc += a.w;
    s2[4] = acc; acc += b.x;
    s2[5] = acc; acc += b.y;
    s2[6] = acc; acc += b.z;
    s2[7] = acc;
    ((int4*)(start2 + i * 8))[0] = make_int4(s2[0], s2[1], s2[2], s2[3]);
    ((int4*)(start2 + i * 8))[1] = make_int4(s2[4], s2[5], s2[6], s2[7]);
    ((int4*)(cursor2 + i * 8))[0] = make_int4(s2[0], s2[1], s2[2], s2[3]);
    ((int4*)(cursor2 + i * 8))[1] = make_int4(s2[4], s2[5], s2[6], s2[7]);
}

__global__ __launch_bounds__(256) void k_fill(const int* __restrict__ src, const int* __restrict__ dst,
                                              const int* __restrict__ et, int* __restrict__ cursor2,
                                              int* __restrict__ csr) {
    int e = blockIdx.x * 256 + threadIdx.x;
    if (e >= NEDGES) return;
    int pos = atomicAdd(&cursor2[dst[e] * RREL + et[e]], 1);
    csr[pos] = src[e];
}

// ---------------- fused prep: x->bf16 + fragment-major B' layouts ----------------
#define PR0 (NNODES * 32)
#define PR1 (2048 * 256)
#define PR2 (256 * 256)
#define PR3 (1024 * 256)
__global__ __launch_bounds__(256) void k_prep(const float* __restrict__ x, const float* __restrict__ Wrel,
                                              const float* __restrict__ Wroot,
                                              const float* __restrict__ Wq, const float* __restrict__ Wk,
                                              const float* __restrict__ Wv, const float* __restrict__ Ws,
                                              const float* __restrict__ bq, const float* __restrict__ bk,
                                              const float* __restrict__ bv, const float* __restrict__ bs,
                                              unsigned short* __restrict__ xb, unsigned short* __restrict__ BtAp,
                                              unsigned short* __restrict__ B2p, float* __restrict__ bias2) {
    int i = blockIdx.x * 256 + threadIdx.x;
    if (i < PR0) {
        const float4* p = (const float4*)(x + (size_t)i * 8);
        float4 v0 = p[0], v1 = p[1];
        u16x8 w;
        w[0] = f2bf(v0.x); w[1] = f2bf(v0.y); w[2] = f2bf(v0.z); w[3] = f2bf(v0.w);
        w[4] = f2bf(v1.x); w[5] = f2bf(v1.y); w[6] = f2bf(v1.z); w[7] = f2bf(v1.w);
        *(u16x8*)(xb + (size_t)i * 8) = w;
    } else if (i < PR0 + PR1) {
        int idx = i - PR0;
        int e = idx & 7, ln = (idx >> 3) & 63, f = (idx >> 9) & 3, w = (idx >> 11) & 3, ks = idx >> 13;
        int h = w * 64 + f * 16 + (ln & 15);
        int k = ks * 32 + ((ln >> 4) << 3) + e;
        int r = k >> 8, g = k & 255;
        BtAp[idx] = f2bf(Wrel[(size_t)r * 65536 + (size_t)g * 256 + h]);
    } else if (i < PR0 + PR1 + PR2) {
        int idx = i - PR0 - PR1;
        int e = idx & 7, ln = (idx >> 3) & 63, f = (idx >> 9) & 3, w = (idx >> 11) & 3, ks2 = idx >> 13;
        int h = w * 64 + f * 16 + (ln & 15);
        int kk = ks2 * 32 + ((ln >> 4) << 3) + e;
        BtAp[PR1 + idx] = f2bf(Wroot[(size_t)kk * 256 + h]);
    } else {
        int idx = i - PR0 - PR1 - PR2;
        int e = idx & 7, ln = (idx >> 3) & 63, f = (idx >> 9) & 3, w = (idx >> 11) & 3;
        int ks = (idx >> 13) & 7, ct = idx >> 16;
        int c = ct * 256 + w * 64 + f * 16 + (ln & 15);
        int g = ks * 32 + ((ln >> 4) << 3) + e;
        const float* W = (c < 256) ? Wq : (c < 512) ? Wk : (c < 768) ? Wv : Ws;
        int cc = c & 255;
        B2p[idx] = f2bf(W[(size_t)g * 256 + cc]);
        if (ks == 0 && e == 0 && (ln >> 4) == 0) {
            const float* B = (c < 256) ? bq : (c < 512) ? bk : (c < 768) ? bv : bs;
            bias2[c] = B[cc];
        }
    }
}

// ---------------- mean-gather: one wave per (node, rel); S[N][2048]; edges batched x8 ----------------
__global__ __launch_bounds__(256) void k_mean(const unsigned short* __restrict__ xb, const int* __restrict__ csr,
                                              const int* __restrict__ start2, const int* __restrict__ cnt,
                                              unsigned short* __restrict__ S) {
    int pid = blockIdx.x * 4 + (threadIdx.x >> 6);
    int lane = threadIdx.x & 63;
    if (pid >= NNODES * 8) return;
    int s0 = start2[pid], n = cnt[pid];
    float4 acc = make_float4(0.f, 0.f, 0.f, 0.f);
    int j = 0;
    for (; j + 8 <= n; j += 8) {
        int sidx[8];
        #pragma unroll
        for (int t = 0; t < 8; t++) sidx[t] = csr[s0 + j + t];
        ushort4 yy[8];
        #pragma unroll
        for (int t = 0; t < 8; t++)
            yy[t] = *(const ushort4*)(xb + (size_t)sidx[t] * 256 + lane * 4);
        #pragma unroll
        for (int t = 0; t < 8; t++) {
            acc.x += bf2f(yy[t].x);
            acc.y += bf2f(yy[t].y);
            acc.z += bf2f(yy[t].z);
            acc.w += bf2f(yy[t].w);
        }
    }
    for (; j + 4 <= n; j += 4) {
        int sa = csr[s0 + j], sb = csr[s0 + j + 1], sc2 = csr[s0 + j + 2], sd = csr[s0 + j + 3];
        ushort4 ya = *(const ushort4*)(xb + (size_t)sa * 256 + lane * 4);
        ushort4 yb = *(const ushort4*)(xb + (size_t)sb * 256 + lane * 4);
        ushort4 yc = *(const ushort4*)(xb + (size_t)sc2 * 256 + lane * 4);
        ushort4 yd = *(const ushort4*)(xb + (size_t)sd * 256 + lane * 4);
        acc.x += bf2f(ya.x) + bf2f(yb.x) + bf2f(yc.x) + bf2f(yd.x);
        acc.y += bf2f(ya.y) + bf2f(yb.y) + bf2f(yc.y) + bf2f(yd.y);
        acc.z += bf2f(ya.z) + bf2f(yb.z) + bf2f(yc.z) + bf2f(yd.z);
        acc.w += bf2f(ya.w) + bf2f(yb.w) + bf2f(yc.w) + bf2f(yd.w);
    }
    for (; j < n; j++) {
        int sa = csr[s0 + j];
        ushort4 ya = *(const ushort4*)(xb + (size_t)sa * 256 + lane * 4);
        acc.x += bf2f(ya.x);
        acc.y += bf2f(ya.y);
        acc.z += bf2f(ya.z);
        acc.w += bf2f(ya.w);
    }
    float sc = 1.0f / (float)(n > 0 ? n : 1);
    ushort4 o;
    o.x = f2bf(acc.x * sc); o.y = f2bf(acc.y * sc);
    o.z = f2bf(acc.z * sc); o.w = f2bf(acc.w * sc);
    *(ushort4*)(S + (size_t)(pid >> 3) * 2048 + (pid & 7) * 256 + lane * 4) = o;
}

// ---------------- GEMM v10: 32x256 tile, B from L2 (fragment-major), 2-deep prefetch rings ----------------
// MODE 5: A = [S (ks<64, stride 2048) | x_bf (ks>=64, stride 256)]; bf16 out = acc + bias (NC=256)
// MODE 3: single A (stride K); ct<3 -> bf16 QKV + bias (NC=768); ct==3 -> f32 skip C2 + bias
template<int MODE>
__global__ __launch_bounds__(256) void k_gemm10(const unsigned short* __restrict__ A,
                                                const unsigned short* __restrict__ A2,
                                                const unsigned short* __restrict__ Bp,
                                                const float* __restrict__ bias,
                                                unsigned short* __restrict__ C, float* __restrict__ C2,
                                                int M, int K, int nks, int nct, int q, int rr) {
    __shared__ __align__(16) unsigned short SH[8448];   // A dbuf 2x2KB; epilogue bounce [32][264]

    int bid = blockIdx.x;
    int xcd = bid & 7, idx = bid >> 3;
    int base = (xcd < rr) ? xcd * (q + 1) : rr * (q + 1) + (xcd - rr) * q;
    int nid = base + idx;
    int rowT = nid / nct, ct = nid - rowT * nct;
    int brow = rowT * 32;

    int tid = threadIdx.x;
    int lane = tid & 63, w = tid >> 6;
    int lr = lane & 15, lq = lane >> 4;

    bool astage = tid < 128;
    int arow = (tid >> 2) & 31, ac = tid & 3;
    int grow = brow + arow;
    const unsigned short* gS = (MODE == 5) ? (A + (size_t)grow * 2048 + ac * 8)
                                           : (A + (size_t)grow * K + ac * 8);
    const unsigned short* gX = (MODE == 5) ? (A2 + (size_t)grow * 256 + ac * 8) : nullptr;
    bool aok = astage && grow < M;
    int awoff = arow * 32 + ac * 8;
    const u16x8 zz = {0, 0, 0, 0, 0, 0, 0, 0};

    const unsigned short* gB = Bp + ((size_t)ct * nks) * 8192 + ((size_t)(w * 4) * 64 + lane) * 8;

    auto aLoad = [&](int kss) -> u16x8 {
        if (!aok) return zz;
        if (MODE == 5) {
            return (kss < 64) ? *(const u16x8*)(gS + (size_t)kss * 32)
                              : *(const u16x8*)(gX + (size_t)(kss - 64) * 32);
        }
        return *(const u16x8*)(gS + (size_t)kss * 32);
    };

    u16x8 raA = aLoad(0);
    u16x8 raB = (nks > 1) ? aLoad(1) : zz;
    u16x8 rb0[4], rb1[4];
    #pragma unroll
    for (int f = 0; f < 4; f++) rb0[f] = *(const u16x8*)(gB + f * 512);
    #pragma unroll
    for (int f = 0; f < 4; f++) rb1[f] = (nks > 1) ? *(const u16x8*)(gB + 8192 + f * 512) : zz;

    f32x4 acc[2][4];
    #pragma unroll
    for (int i = 0; i < 2; i++)
        #pragma unroll
        for (int j = 0; j < 4; j++) acc[i][j] = (f32x4){0.f, 0.f, 0.f, 0.f};

    int cur = 0;
    for (int ks = 0; ks < nks; ks++) {
        if (astage) *(u16x8*)(SH + cur * 1024 + awoff) = raA;
        __syncthreads();
        raA = raB;
        u16x8 rbu[4];
        #pragma unroll
        for (int f = 0; f < 4; f++) { rbu[f] = rb0[f]; rb0[f] = rb1[f]; }
        if (ks + 2 < nks) {
            raB = aLoad(ks + 2);
            #pragma unroll
            for (int f = 0; f < 4; f++)
                rb1[f] = *(const u16x8*)(gB + (size_t)(ks + 2) * 8192 + f * 512);
        }
        bf16x8 af[2];
        #pragma unroll
        for (int i = 0; i < 2; i++)
            af[i] = *(const bf16x8*)(SH + cur * 1024 + (i * 16 + lr) * 32 + lq * 8);
        #pragma unroll
        for (int i = 0; i < 2; i++)
            #pragma unroll
            for (int j = 0; j < 4; j++)
                acc[i][j] = __builtin_amdgcn_mfma_f32_16x16x32_bf16(af[i], (bf16x8)rbu[j], acc[i][j], 0, 0, 0);
        cur ^= 1;
    }

    __syncthreads();

    bool f32out = (MODE == 3) && (ct == 3);
    if (!f32out) {
        float bb[4];
        #pragma unroll
        for (int j = 0; j < 4; j++)
            bb[j] = bias[((MODE == 5) ? 0 : ct * 256) + w * 64 + j * 16 + lr];
        #pragma unroll
        for (int i = 0; i < 2; i++)
            #pragma unroll
            for (int j = 0; j < 4; j++)
                #pragma unroll
                for (int r = 0; r < 4; r++) {
                    int lrow = i * 16 + lq * 4 + r;
                    int col = w * 64 + j * 16 + lr;
                    SH[lrow * 264 + col] = f2bf(acc[i][j][r] + bb[j]);
                }
        __syncthreads();
        int row = tid >> 3;
        int ch = (tid & 7) * 32;
        int gr2 = brow + row;
        if (gr2 < M) {
            unsigned short* dstp = (MODE == 5) ? (C + (size_t)gr2 * 256 + ch)
                                               : (C + (size_t)gr2 * 768 + ct * 256 + ch);
            const unsigned short* srcp = SH + row * 264 + ch;
            #pragma unroll
            for (int k = 0; k < 4; k++)
                *(u16x8*)(dstp + k * 8) = *(const u16x8*)(srcp + k * 8);
        }
    } else {
        #pragma unroll
        for (int i = 0; i < 2; i++)
            #pragma unroll
            for (int j = 0; j < 4; j++) {
                int col = w * 64 + j * 16 + lr;
                float bv2 = bias[768 + col];
                #pragma unroll
                for (int r = 0; r < 4; r++) {
                    int gr = brow + i * 16 + lq * 4 + r;
                    if (gr < M) C2[(size_t)gr * 256 + col] = acc[i][j][r] + bv2;
                }
            }
    }
}

// ---------------- fused attention (round-13 best): one wave per node, online softmax, edges x8 ----------------
__global__ __launch_bounds__(256) void k_attn(const unsigned short* __restrict__ QKV, const int* __restrict__ csr,
                                              const int* __restrict__ start2, const int* __restrict__ deg,
                                              float* __restrict__ out) {
    int node = blockIdx.x * 4 + (threadIdx.x >> 6);
    int lane = threadIdx.x & 63;
    if (node >= NNODES) return;
    int s0 = start2[node * 8], n = deg[node];
    if (n == 0) return;
    ushort4 qu = *(const ushort4*)(QKV + (size_t)node * 768 + lane * 4);
    float q0 = bf2f(qu.x), q1 = bf2f(qu.y), q2 = bf2f(qu.z), q3 = bf2f(qu.w);
    float m = -INFINITY, den = 0.f;
    float4 acc = make_float4(0.f, 0.f, 0.f, 0.f);
    int j = 0;
    for (; j + 8 <= n; j += 8) {
        int sidx[8];
        #pragma unroll
        for (int t = 0; t < 8; t++) sidx[t] = csr[s0 + j + t];
        ushort4 kk[8], vv[8];
        #pragma unroll
        for (int t = 0; t < 8; t++) {
            const unsigned short* bp = QKV + (size_t)sidx[t] * 768;
            kk[t] = *(const ushort4*)(bp + 256 + lane * 4);
            vv[t] = *(const ushort4*)(bp + 512 + lane * 4);
        }
        float p[8];
        #pragma unroll
        for (int t = 0; t < 8; t++)
            p[t] = q0 * bf2f(kk[t].x) + q1 * bf2f(kk[t].y) + q2 * bf2f(kk[t].z) + q3 * bf2f(kk[t].w);
        #pragma unroll
        for (int o = 32; o; o >>= 1) {
            #pragma unroll
            for (int t = 0; t < 8; t++) p[t] += __shfl_xor(p[t], o);
        }
        float pm = p[0];
        #pragma unroll
        for (int t = 1; t < 8; t++) pm = fmaxf(pm, p[t]);
        pm *= 0.0625f;
        if (pm > m) {
            float rr = __expf(m - pm);   // first batch: exp(-inf)=0
            den *= rr;
            acc.x *= rr; acc.y *= rr; acc.z *= rr; acc.w *= rr;
            m = pm;
        }
        #pragma unroll
        for (int t = 0; t < 8; t++) {
            float e = __expf(p[t] * 0.0625f - m);
            den += e;
            acc.x += e * bf2f(vv[t].x);
            acc.y += e * bf2f(vv[t].y);
            acc.z += e * bf2f(vv[t].z);
            acc.w += e * bf2f(vv[t].w);
        }
    }
    for (; j < n; j++) {
        const unsigned short* basep = QKV + (size_t)csr[s0 + j] * 768;
        ushort4 ku = *(const ushort4*)(basep + 256 + lane * 4);
        ushort4 vu = *(const ushort4*)(basep + 512 + lane * 4);
        float p = q0 * bf2f(ku.x) + q1 * bf2f(ku.y) + q2 * bf2f(ku.z) + q3 * bf2f(ku.w);
        #pragma unroll
        for (int o = 32; o; o >>= 1) p += __shfl_xor(p, o);
        p *= 0.0625f;
        if (p > m) {
            float rr = __expf(m - p);
            den *= rr;
            acc.x *= rr; acc.y *= rr; acc.z *= rr; acc.w *= rr;
            m = p;
        }
        float ex = __expf(p - m);
        den += ex;
        acc.x += ex * bf2f(vu.x); acc.y += ex * bf2f(vu.y);
        acc.z += ex * bf2f(vu.z); acc.w += ex * bf2f(vu.w);
    }
    float rinv = 1.0f / fmaxf(den, 1e-16f);
    float4* o4 = (float4*)(out + (size_t)node * 256);
    float4 o = o4[lane];
    o.x += acc.x * rinv; o.y += acc.y * rinv; o.z += acc.z * rinv; o.w += acc.w * rinv;
    o4[lane] = o;
}

// ---------------- batch norm + leaky relu ----------------
__global__ __launch_bounds__(256) void k_bnstats(const float* __restrict__ out, float* __restrict__ sums,
                                                 float* __restrict__ sumsq) {
    int c = threadIdx.x;
    int rows_per = (NNODES + gridDim.x - 1) / gridDim.x;
    int r0 = blockIdx.x * rows_per;
    int r1 = r0 + rows_per; if (r1 > NNODES) r1 = NNODES;
    float s = 0.f, ss = 0.f;
    for (int r = r0; r < r1; r++) {
        float v = out[(size_t)r * 256 + c];
        s += v; ss += v * v;
    }
    atomicAdd(&sums[c], s);
    atomicAdd(&sumsq[c], ss);
}

__global__ __launch_bounds__(256) void k_bnapply(float4* __restrict__ out, const float* __restrict__ sums,
                                                 const float* __restrict__ sumsq, const float* __restrict__ gamma,
                                                 const float* __restrict__ beta) {
    int i = blockIdx.x * 256 + threadIdx.x;
    if (i >= NNODES * 64) return;
    int c4 = i & 63;
    float4 sc, sh;
    #pragma unroll
    for (int t = 0; t < 4; t++) {
        int c = c4 * 4 + t;
        float mu = sums[c] * (1.0f / NNODES);
        float var = sumsq[c] * (1.0f / NNODES) - mu * mu;
        float s = gamma[c] * rsqrtf(fmaxf(var, 0.f) + EPSBN);
        ((float*)&sc)[t] = s;
        ((float*)&sh)[t] = beta[c] - mu * s;
    }
    float4 v = out[i];
    v.x = v.x * sc.x + sh.x; v.y = v.y * sc.y + sh.y;
    v.z = v.z * sc.z + sh.z; v.w = v.w * sc.w + sh.w;
    v.x = v.x > 0.f ? v.x : 0.01f * v.x;
    v.y = v.y > 0.f ? v.y : 0.01f * v.y;
    v.z = v.z > 0.f ? v.z : 0.01f * v.z;
    v.w = v.w > 0.f ? v.w : 0.01f * v.w;
    out[i] = v;
}

extern "C" void kernel_launch(void* const* d_in, const int* in_sizes, int n_in,
                              void* d_out, int out_size, void* d_ws, size_t ws_size,
                              hipStream_t stream) {
    const float* x = (const float*)d_in[0];
    const int* ei = (const int*)d_in[1];
    const int* etype = (const int*)d_in[2];
    const float* Wrel = (const float*)d_in[3];
    const float* Wroot = (const float*)d_in[4];
    const float* b1 = (const float*)d_in[5];
    const float* Wq = (const float*)d_in[6];
    const float* bq = (const float*)d_in[7];
    const float* Wk = (const float*)d_in[8];
    const float* bk = (const float*)d_in[9];
    const float* Wv = (const float*)d_in[10];
    const float* bv = (const float*)d_in[11];
    const float* Ws = (const float*)d_in[12];
    const float* bs = (const float*)d_in[13];
    const float* gamma = (const float*)d_in[14];
    const float* beta = (const float*)d_in[15];
    float* out = (float*)d_out;

    const int* srcA = ei;
    const int* dstA = ei + NEDGES;

    char* w = (char*)d_ws;
    unsigned short* S = (unsigned short*)w;     w += (size_t)NNODES * 2048 * 2;
    unsigned short* x_bf = (unsigned short*)w;  w += (size_t)NNODES * 256 * 2;
    unsigned short* x1bf = (unsigned short*)w;  w += (size_t)NNODES * 256 * 2;
    unsigned short* QKVbf = (unsigned short*)w; w += (size_t)NNODES * 768 * 2;
    unsigned short* BtAp = (unsigned short*)w;  w += (size_t)256 * 2304 * 2;
    unsigned short* B2p = (unsigned short*)w;   w += (size_t)1024 * 256 * 2;
    float* bias2 = (float*)w;                   w += 1024 * 4;
    int* cnt = (int*)w;                         w += (size_t)NNODES * RREL * 4;
    int* deg = (int*)w;                         w += (size_t)NNODES * 4;
    int* startv = (int*)w;                      w += (size_t)NNODES * 4;
    int* start2 = (int*)w;                      w += (size_t)NNODES * RREL * 4;
    int* cursor2 = (int*)w;                     w += (size_t)NNODES * RREL * 4;
    int* csr = (int*)w;                         w += (size_t)NEDGES * 4;
    float* sums = (float*)w;                    w += 1024;
    float* sumsq = (float*)w;                   w += 1024;
    size_t need = (size_t)(w - (char*)d_ws);
    if (ws_size < need) return;

    hipMemsetAsync(cnt, 0, (size_t)NNODES * RREL * 4, stream);
    hipMemsetAsync(sums, 0, 2048, stream);

    k_count<<<(NEDGES + 255) / 256, 256, 0, stream>>>(dstA, etype, cnt);
    k_deg<<<(NNODES + 255) / 256, 256, 0, stream>>>(cnt, deg);
    k_scan<<<1, 256, 0, stream>>>(deg, startv);
    k_sub<<<(NNODES + 255) / 256, 256, 0, stream>>>(cnt, startv, start2, cursor2);
    k_fill<<<(NEDGES + 255) / 256, 256, 0, stream>>>(srcA, dstA, etype, cursor2, csr);

    k_prep<<<(PR0 + PR1 + PR2 + PR3) / 256, 256, 0, stream>>>(x, Wrel, Wroot, Wq, Wk, Wv, Ws,
                                                              bq, bk, bv, bs, x_bf, BtAp, B2p, bias2);

    // S[d][r*256..] = mean_r(x) (bf16); one wave per (node, rel)
    k_mean<<<(NNODES * 8 + 3) / 4, 256, 0, stream>>>(x_bf, csr, start2, cnt, S);

    // x1bf = bf16([S | x_bf] @ [W_0..W_7; W_root] + b1); 32x256 tiles, 625 blocks
    {
        int nwg = 625;
        int q = nwg / 8, rr = nwg % 8;
        k_gemm10<5><<<nwg, 256, 0, stream>>>(S, x_bf, BtAp, b1, x1bf, nullptr, NNODES, 2304, 72, 1, q, rr);
    }

    // [q|k|v -> QKVbf, skip -> out] = x1 @ [Wq|Wk|Wv|Wskip] + bias2; 32x256 tiles, 2500 blocks
    {
        int nwg = 625 * 4;
        int q = nwg / 8, rr = nwg % 8;
        k_gemm10<3><<<nwg, 256, 0, stream>>>(x1bf, nullptr, B2p, bias2, QKVbf, out, NNODES, 256, 8, 4, q, rr);
    }

    // fused attention: one wave per node (round-13 best)
    k_attn<<<(NNODES + 3) / 4, 256, 0, stream>>>(QKVbf, csr, start2, deg, out);

    k_bnstats<<<400, 256, 0, stream>>>(out, sums, sumsq);
    k_bnapply<<<(NNODES * 64 + 255) / 256, 256, 0, stream>>>((float4*)out, sums, sumsq, gamma, beta);
}

// Round 16
// 266.732 us; speedup vs baseline: 1.0619x; 1.0244x over previous
//
#include <hip/hip_runtime.h>
#include <math.h>

#define NNODES 20000
#define NEDGES 320000
#define RREL 8
#define EPSBN 1e-5f

typedef float f32x4 __attribute__((ext_vector_type(4)));
typedef __bf16 bf16x8 __attribute__((ext_vector_type(8)));
typedef unsigned short u16x8 __attribute__((ext_vector_type(8)));

static __device__ __forceinline__ unsigned short f2bf(float f) {
    unsigned int x = __builtin_bit_cast(unsigned int, f);
    unsigned int r = x + 0x7FFFu + ((x >> 16) & 1u);
    return (unsigned short)(r >> 16);
}
static __device__ __forceinline__ float bf2f(unsigned short u) {
    unsigned int x = ((unsigned int)u) << 16;
    return __builtin_bit_cast(float, x);
}

// ---------------- CSR build (sorted by (dst, rel)) ----------------
__global__ __launch_bounds__(256) void k_count(const int* __restrict__ dst, const int* __restrict__ et,
                                               int* __restrict__ cnt) {
    int e = blockIdx.x * 256 + threadIdx.x;
    if (e >= NEDGES) return;
    atomicAdd(&cnt[dst[e] * RREL + et[e]], 1);
}

__global__ __launch_bounds__(256) void k_deg(const int* __restrict__ cnt, int* __restrict__ deg) {
    int i = blockIdx.x * 256 + threadIdx.x;
    if (i >= NNODES) return;
    const int4* p = (const int4*)(cnt + i * 8);
    int4 a = p[0], b = p[1];
    deg[i] = a.x + a.y + a.z + a.w + b.x + b.y + b.z + b.w;
}

__global__ __launch_bounds__(256) void k_scan(const int* __restrict__ deg, int* __restrict__ start) {
    __shared__ int part[256];
    int t = threadIdx.x;
    int i0 = t * 80;
    int s = 0;
    if (i0 < NNODES) {
        for (int i = 0; i < 80; i += 4) {
            int4 v = *(const int4*)(deg + i0 + i);
            s += v.x + v.y + v.z + v.w;
        }
    }
    part[t] = s;
    __syncthreads();
    if (t == 0) {
        int acc = 0;
        for (int j = 0; j < 256; j++) { int v = part[j]; part[j] = acc; acc += v; }
    }
    __syncthreads();
    int acc = part[t];
    if (i0 < NNODES) {
        for (int i = 0; i < 80; i += 4) {
            int4 v = *(const int4*)(deg + i0 + i);
            int4 st;
            st.x = acc; acc += v.x;
            st.y = acc; acc += v.y;
            st.z = acc; acc += v.z;
            st.w = acc; acc += v.w;
            *(int4*)(start + i0 + i) = st;
        }
    }
}

__global__ __launch_bounds__(256) void k_sub(const int* __restrict__ cnt, const int* __restrict__ start,
                                             int* __restrict__ start2, int* __restrict__ cursor2) {
    int i = blockIdx.x * 256 + threadIdx.x;
    if (i >= NNODES) return;
    const int4* p = (const int4*)(cnt + i * 8);
    int4 a = p[0], b = p[1];
    int acc = start[i];
    int s2[8];
    s2[0] = acc; acc += a.x;
    s2[1] = acc; acc += a.y;
    s2[2] = acc; acc += a.z;
    s2[3] = acc; acc += a.w;
    s2[4] = acc; acc += b.x;
    s2[5] = acc; acc += b.y;
    s2[6] = acc; acc += b.z;
    s2[7] = acc;
    ((int4*)(start2 + i * 8))[0] = make_int4(s2[0], s2[1], s2[2], s2[3]);
    ((int4*)(start2 + i * 8))[1] = make_int4(s2[4], s2[5], s2[6], s2[7]);
    ((int4*)(cursor2 + i * 8))[0] = make_int4(s2[0], s2[1], s2[2], s2[3]);
    ((int4*)(cursor2 + i * 8))[1] = make_int4(s2[4], s2[5], s2[6], s2[7]);
}

__global__ __launch_bounds__(256) void k_fill(const int* __restrict__ src, const int* __restrict__ dst,
                                              const int* __restrict__ et, int* __restrict__ cursor2,
                                              int* __restrict__ csr) {
    int e = blockIdx.x * 256 + threadIdx.x;
    if (e >= NEDGES) return;
    int pos = atomicAdd(&cursor2[dst[e] * RREL + et[e]], 1);
    csr[pos] = src[e];
}

// ---------------- fused prep: x->bf16 + fragment-major B' layouts ----------------
// B' layout: flat[(((ct*nks + ks)*4 + w)*4 + f)*64 + lane]*8 + e
//   = Bt[ct*256 + w*64 + f*16 + (lane&15)][ks*32 + (lane>>4)*8 + e]
#define PR0 (NNODES * 32)
#define PR1 (2048 * 256)
#define PR2 (256 * 256)
#define PR3 (1024 * 256)
__global__ __launch_bounds__(256) void k_prep(const float* __restrict__ x, const float* __restrict__ Wrel,
                                              const float* __restrict__ Wroot,
                                              const float* __restrict__ Wq, const float* __restrict__ Wk,
                                              const float* __restrict__ Wv, const float* __restrict__ Ws,
                                              const float* __restrict__ bq, const float* __restrict__ bk,
                                              const float* __restrict__ bv, const float* __restrict__ bs,
                                              unsigned short* __restrict__ xb, unsigned short* __restrict__ BtAp,
                                              unsigned short* __restrict__ B2p, float* __restrict__ bias2) {
    int i = blockIdx.x * 256 + threadIdx.x;
    if (i < PR0) {
        const float4* p = (const float4*)(x + (size_t)i * 8);
        float4 v0 = p[0], v1 = p[1];
        u16x8 w;
        w[0] = f2bf(v0.x); w[1] = f2bf(v0.y); w[2] = f2bf(v0.z); w[3] = f2bf(v0.w);
        w[4] = f2bf(v1.x); w[5] = f2bf(v1.y); w[6] = f2bf(v1.z); w[7] = f2bf(v1.w);
        *(u16x8*)(xb + (size_t)i * 8) = w;
    } else if (i < PR0 + PR1) {
        int idx = i - PR0;
        int e = idx & 7, ln = (idx >> 3) & 63, f = (idx >> 9) & 3, w = (idx >> 11) & 3, ks = idx >> 13;
        int h = w * 64 + f * 16 + (ln & 15);
        int k = ks * 32 + ((ln >> 4) << 3) + e;
        int r = k >> 8, g = k & 255;
        BtAp[idx] = f2bf(Wrel[(size_t)r * 65536 + (size_t)g * 256 + h]);
    } else if (i < PR0 + PR1 + PR2) {
        int idx = i - PR0 - PR1;
        int e = idx & 7, ln = (idx >> 3) & 63, f = (idx >> 9) & 3, w = (idx >> 11) & 3, ks2 = idx >> 13;
        int h = w * 64 + f * 16 + (ln & 15);
        int kk = ks2 * 32 + ((ln >> 4) << 3) + e;
        BtAp[PR1 + idx] = f2bf(Wroot[(size_t)kk * 256 + h]);
    } else {
        int idx = i - PR0 - PR1 - PR2;
        int e = idx & 7, ln = (idx >> 3) & 63, f = (idx >> 9) & 3, w = (idx >> 11) & 3;
        int ks = (idx >> 13) & 7, ct = idx >> 16;
        int c = ct * 256 + w * 64 + f * 16 + (ln & 15);
        int g = ks * 32 + ((ln >> 4) << 3) + e;
        const float* W = (c < 256) ? Wq : (c < 512) ? Wk : (c < 768) ? Wv : Ws;
        int cc = c & 255;
        B2p[idx] = f2bf(W[(size_t)g * 256 + cc]);
        if (ks == 0 && e == 0 && (ln >> 4) == 0) {
            const float* B = (c < 256) ? bq : (c < 512) ? bk : (c < 768) ? bv : bs;
            bias2[c] = B[cc];
        }
    }
}

// ---------------- mean-gather: S[d] = [mean_r(x) r=0..7 | x], bf16 ----------------
__global__ __launch_bounds__(256) void k_mean(const unsigned short* __restrict__ xb, const int* __restrict__ csr,
                                              const int* __restrict__ start2, const int* __restrict__ cnt,
                                              unsigned short* __restrict__ S) {
    int node = blockIdx.x * 4 + (threadIdx.x >> 6);
    int lane = threadIdx.x & 63;
    if (node >= NNODES) return;
    ushort4 xr = *(const ushort4*)(xb + (size_t)node * 256 + lane * 4);
    *(ushort4*)(S + (size_t)node * 2304 + 2048 + lane * 4) = xr;
    int base = node * 8;
    for (int r = 0; r < 8; r++) {
        int s0 = start2[base + r];
        int n = cnt[base + r];
        float4 acc = make_float4(0.f, 0.f, 0.f, 0.f);
        int j = 0;
        for (; j + 2 <= n; j += 2) {
            int sa = csr[s0 + j], sb = csr[s0 + j + 1];
            ushort4 ya = *(const ushort4*)(xb + (size_t)sa * 256 + lane * 4);
            ushort4 yb = *(const ushort4*)(xb + (size_t)sb * 256 + lane * 4);
            acc.x += bf2f(ya.x) + bf2f(yb.x);
            acc.y += bf2f(ya.y) + bf2f(yb.y);
            acc.z += bf2f(ya.z) + bf2f(yb.z);
            acc.w += bf2f(ya.w) + bf2f(yb.w);
        }
        if (j < n) {
            int sa = csr[s0 + j];
            ushort4 ya = *(const ushort4*)(xb + (size_t)sa * 256 + lane * 4);
            acc.x += bf2f(ya.x);
            acc.y += bf2f(ya.y);
            acc.z += bf2f(ya.z);
            acc.w += bf2f(ya.w);
        }
        float sc = 1.0f / (float)(n > 0 ? n : 1);
        ushort4 o;
        o.x = f2bf(acc.x * sc); o.y = f2bf(acc.y * sc);
        o.z = f2bf(acc.z * sc); o.w = f2bf(acc.w * sc);
        *(ushort4*)(S + (size_t)node * 2304 + r * 256 + lane * 4) = o;
    }
}

// ---------------- GEMM v10: 32x256 tile, B from L2 (fragment-major), 2-deep prefetch rings ----------------
// 4 waves, each 32x64 out (8 MFMA/k-step). A stage [32][32] linear (bank-uniform both sides),
// 2x2KB dbuf; A and B prefetched 2 k-steps ahead. 1 barrier/k-step. XCD-bijective swizzle.
// MODE 5: bf16 out = acc + bias (x1bf, NC=256, nct=1)
// MODE 3: ct<3 -> bf16 QKV + bias (NC=768); ct==3 -> f32 skip C2 + bias (direct)
template<int MODE>
__global__ __launch_bounds__(256) void k_gemm10(const unsigned short* __restrict__ A,
                                                const unsigned short* __restrict__ Bp,
                                                const float* __restrict__ bias,
                                                unsigned short* __restrict__ C, float* __restrict__ C2,
                                                int M, int K, int nks, int nct, int q, int rr) {
    __shared__ __align__(16) unsigned short SH[8448];   // A dbuf 2x2KB (0..2048); epilogue bounce [32][264]

    int bid = blockIdx.x;
    int xcd = bid & 7, idx = bid >> 3;
    int base = (xcd < rr) ? xcd * (q + 1) : rr * (q + 1) + (xcd - rr) * q;
    int nid = base + idx;
    int rowT = nid / nct, ct = nid - rowT * nct;
    int brow = rowT * 32;

    int tid = threadIdx.x;
    int lane = tid & 63, w = tid >> 6;
    int lr = lane & 15, lq = lane >> 4;

    // A staging (first 128 threads): thread -> (row, 16B k-chunk)
    bool astage = tid < 128;
    int arow = (tid >> 2) & 31, ac = tid & 3;
    const unsigned short* gA = A + (size_t)(brow + arow) * K + ac * 8;
    bool aok = astage && (brow + arow) < M;
    int awoff = arow * 32 + ac * 8;
    const u16x8 zz = {0, 0, 0, 0, 0, 0, 0, 0};

    // B fragment-major: per wave/frag contiguous 1KB; k-step stride 8192 shorts
    const unsigned short* gB = Bp + ((size_t)ct * nks) * 8192 + ((size_t)(w * 4) * 64 + lane) * 8;

    // prefetch rings (2-deep)
    u16x8 raA = aok ? *(const u16x8*)gA : zz;
    u16x8 raB = (aok && nks > 1) ? *(const u16x8*)(gA + 32) : zz;
    u16x8 rb0[4], rb1[4];
    #pragma unroll
    for (int f = 0; f < 4; f++) rb0[f] = *(const u16x8*)(gB + f * 512);
    #pragma unroll
    for (int f = 0; f < 4; f++) rb1[f] = (nks > 1) ? *(const u16x8*)(gB + 8192 + f * 512) : zz;

    f32x4 acc[2][4];
    #pragma unroll
    for (int i = 0; i < 2; i++)
        #pragma unroll
        for (int j = 0; j < 4; j++) acc[i][j] = (f32x4){0.f, 0.f, 0.f, 0.f};

    int cur = 0;
    for (int ks = 0; ks < nks; ks++) {
        if (astage) *(u16x8*)(SH + cur * 1024 + awoff) = raA;
        __syncthreads();
        raA = raB;
        u16x8 rbu[4];
        #pragma unroll
        for (int f = 0; f < 4; f++) { rbu[f] = rb0[f]; rb0[f] = rb1[f]; }
        if (ks + 2 < nks) {
            raB = aok ? *(const u16x8*)(gA + (size_t)(ks + 2) * 32) : zz;
            #pragma unroll
            for (int f = 0; f < 4; f++)
                rb1[f] = *(const u16x8*)(gB + (size_t)(ks + 2) * 8192 + f * 512);
        }
        bf16x8 af[2];
        #pragma unroll
        for (int i = 0; i < 2; i++)
            af[i] = *(const bf16x8*)(SH + cur * 1024 + (i * 16 + lr) * 32 + lq * 8);
        #pragma unroll
        for (int i = 0; i < 2; i++)
            #pragma unroll
            for (int j = 0; j < 4; j++)
                acc[i][j] = __builtin_amdgcn_mfma_f32_16x16x32_bf16(af[i], (bf16x8)rbu[j], acc[i][j], 0, 0, 0);
        cur ^= 1;
    }

    __syncthreads();   // LDS frag reads done before bounce reuse

    bool f32out = (MODE == 3) && (ct == 3);
    if (!f32out) {
        float bb[4];
        #pragma unroll
        for (int j = 0; j < 4; j++)
            bb[j] = bias[((MODE == 5) ? 0 : ct * 256) + w * 64 + j * 16 + lr];
        #pragma unroll
        for (int i = 0; i < 2; i++)
            #pragma unroll
            for (int j = 0; j < 4; j++)
                #pragma unroll
                for (int r = 0; r < 4; r++) {
                    int lrow = i * 16 + lq * 4 + r;
                    int col = w * 64 + j * 16 + lr;
                    SH[lrow * 264 + col] = f2bf(acc[i][j][r] + bb[j]);
                }
        __syncthreads();
        int row = tid >> 3;
        int ch = (tid & 7) * 32;
        int grow = brow + row;
        if (grow < M) {
            unsigned short* dstp = (MODE == 5) ? (C + (size_t)grow * 256 + ch)
                                               : (C + (size_t)grow * 768 + ct * 256 + ch);
            const unsigned short* srcp = SH + row * 264 + ch;
            #pragma unroll
            for (int k = 0; k < 4; k++)
                *(u16x8*)(dstp + k * 8) = *(const u16x8*)(srcp + k * 8);
        }
    } else {
        #pragma unroll
        for (int i = 0; i < 2; i++)
            #pragma unroll
            for (int j = 0; j < 4; j++) {
                int col = w * 64 + j * 16 + lr;
                float bv2 = bias[768 + col];
                #pragma unroll
                for (int r = 0; r < 4; r++) {
                    int gr = brow + i * 16 + lq * 4 + r;
                    if (gr < M) C2[(size_t)gr * 256 + col] = acc[i][j][r] + bv2;
                }
            }
    }
}

// ---------------- fused attention: one wave per node, online softmax, edges batched x8 ----------------
__global__ __launch_bounds__(256) void k_attn(const unsigned short* __restrict__ QKV, const int* __restrict__ csr,
                                              const int* __restrict__ start2, const int* __restrict__ deg,
                                              float* __restrict__ out) {
    int node = blockIdx.x * 4 + (threadIdx.x >> 6);
    int lane = threadIdx.x & 63;
    if (node >= NNODES) return;
    int s0 = start2[node * 8], n = deg[node];
    if (n == 0) return;
    ushort4 qu = *(const ushort4*)(QKV + (size_t)node * 768 + lane * 4);
    float q0 = bf2f(qu.x), q1 = bf2f(qu.y), q2 = bf2f(qu.z), q3 = bf2f(qu.w);
    float m = -INFINITY, den = 0.f;
    float4 acc = make_float4(0.f, 0.f, 0.f, 0.f);
    int j = 0;
    for (; j + 8 <= n; j += 8) {
        int sidx[8];
        #pragma unroll
        for (int t = 0; t < 8; t++) sidx[t] = csr[s0 + j + t];
        ushort4 kk[8], vv[8];
        #pragma unroll
        for (int t = 0; t < 8; t++) {
            const unsigned short* bp = QKV + (size_t)sidx[t] * 768;
            kk[t] = *(const ushort4*)(bp + 256 + lane * 4);
            vv[t] = *(const ushort4*)(bp + 512 + lane * 4);
        }
        float p[8];
        #pragma unroll
        for (int t = 0; t < 8; t++)
            p[t] = q0 * bf2f(kk[t].x) + q1 * bf2f(kk[t].y) + q2 * bf2f(kk[t].z) + q3 * bf2f(kk[t].w);
        #pragma unroll
        for (int o = 32; o; o >>= 1) {
            #pragma unroll
            for (int t = 0; t < 8; t++) p[t] += __shfl_xor(p[t], o);
        }
        float pm = p[0];
        #pragma unroll
        for (int t = 1; t < 8; t++) pm = fmaxf(pm, p[t]);
        pm *= 0.0625f;
        if (pm > m) {
            float rr = __expf(m - pm);   // first batch: exp(-inf)=0
            den *= rr;
            acc.x *= rr; acc.y *= rr; acc.z *= rr; acc.w *= rr;
            m = pm;
        }
        #pragma unroll
        for (int t = 0; t < 8; t++) {
            float e = __expf(p[t] * 0.0625f - m);
            den += e;
            acc.x += e * bf2f(vv[t].x);
            acc.y += e * bf2f(vv[t].y);
            acc.z += e * bf2f(vv[t].z);
            acc.w += e * bf2f(vv[t].w);
        }
    }
    for (; j < n; j++) {
        const unsigned short* basep = QKV + (size_t)csr[s0 + j] * 768;
        ushort4 ku = *(const ushort4*)(basep + 256 + lane * 4);
        ushort4 vu = *(const ushort4*)(basep + 512 + lane * 4);
        float p = q0 * bf2f(ku.x) + q1 * bf2f(ku.y) + q2 * bf2f(ku.z) + q3 * bf2f(ku.w);
        #pragma unroll
        for (int o = 32; o; o >>= 1) p += __shfl_xor(p, o);
        p *= 0.0625f;
        if (p > m) {
            float rr = __expf(m - p);
            den *= rr;
            acc.x *= rr; acc.y *= rr; acc.z *= rr; acc.w *= rr;
            m = p;
        }
        float ex = __expf(p - m);
        den += ex;
        acc.x += ex * bf2f(vu.x); acc.y += ex * bf2f(vu.y);
        acc.z += ex * bf2f(vu.z); acc.w += ex * bf2f(vu.w);
    }
    float rinv = 1.0f / fmaxf(den, 1e-16f);
    float4* o4 = (float4*)(out + (size_t)node * 256);
    float4 o = o4[lane];
    o.x += acc.x * rinv; o.y += acc.y * rinv; o.z += acc.z * rinv; o.w += acc.w * rinv;
    o4[lane] = o;
}

// ---------------- batch norm + leaky relu ----------------
__global__ __launch_bounds__(256) void k_bnstats(const float* __restrict__ out, float* __restrict__ sums,
                                                 float* __restrict__ sumsq) {
    int c = threadIdx.x;
    int rows_per = (NNODES + gridDim.x - 1) / gridDim.x;
    int r0 = blockIdx.x * rows_per;
    int r1 = r0 + rows_per; if (r1 > NNODES) r1 = NNODES;
    float s = 0.f, ss = 0.f;
    for (int r = r0; r < r1; r++) {
        float v = out[(size_t)r * 256 + c];
        s += v; ss += v * v;
    }
    atomicAdd(&sums[c], s);
    atomicAdd(&sumsq[c], ss);
}

__global__ __launch_bounds__(256) void k_bnapply(float4* __restrict__ out, const float* __restrict__ sums,
                                                 const float* __restrict__ sumsq, const float* __restrict__ gamma,
                                                 const float* __restrict__ beta) {
    int i = blockIdx.x * 256 + threadIdx.x;
    if (i >= NNODES * 64) return;
    int c4 = i & 63;
    float4 sc, sh;
    #pragma unroll
    for (int t = 0; t < 4; t++) {
        int c = c4 * 4 + t;
        float mu = sums[c] * (1.0f / NNODES);
        float var = sumsq[c] * (1.0f / NNODES) - mu * mu;
        float s = gamma[c] * rsqrtf(fmaxf(var, 0.f) + EPSBN);
        ((float*)&sc)[t] = s;
        ((float*)&sh)[t] = beta[c] - mu * s;
    }
    float4 v = out[i];
    v.x = v.x * sc.x + sh.x; v.y = v.y * sc.y + sh.y;
    v.z = v.z * sc.z + sh.z; v.w = v.w * sc.w + sh.w;
    v.x = v.x > 0.f ? v.x : 0.01f * v.x;
    v.y = v.y > 0.f ? v.y : 0.01f * v.y;
    v.z = v.z > 0.f ? v.z : 0.01f * v.z;
    v.w = v.w > 0.f ? v.w : 0.01f * v.w;
    out[i] = v;
}

extern "C" void kernel_launch(void* const* d_in, const int* in_sizes, int n_in,
                              void* d_out, int out_size, void* d_ws, size_t ws_size,
                              hipStream_t stream) {
    const float* x = (const float*)d_in[0];
    const int* ei = (const int*)d_in[1];
    const int* etype = (const int*)d_in[2];
    const float* Wrel = (const float*)d_in[3];
    const float* Wroot = (const float*)d_in[4];
    const float* b1 = (const float*)d_in[5];
    const float* Wq = (const float*)d_in[6];
    const float* bq = (const float*)d_in[7];
    const float* Wk = (const float*)d_in[8];
    const float* bk = (const float*)d_in[9];
    const float* Wv = (const float*)d_in[10];
    const float* bv = (const float*)d_in[11];
    const float* Ws = (const float*)d_in[12];
    const float* bs = (const float*)d_in[13];
    const float* gamma = (const float*)d_in[14];
    const float* beta = (const float*)d_in[15];
    float* out = (float*)d_out;

    const int* srcA = ei;
    const int* dstA = ei + NEDGES;

    char* w = (char*)d_ws;
    unsigned short* S = (unsigned short*)w;     w += (size_t)NNODES * 2304 * 2;   // 92.2 MB
    unsigned short* x_bf = (unsigned short*)w;  w += (size_t)NNODES * 256 * 2;
    unsigned short* x1bf = (unsigned short*)w;  w += (size_t)NNODES * 256 * 2;
    unsigned short* QKVbf = (unsigned short*)w; w += (size_t)NNODES * 768 * 2;
    unsigned short* BtAp = (unsigned short*)w;  w += (size_t)256 * 2304 * 2;
    unsigned short* B2p = (unsigned short*)w;   w += (size_t)1024 * 256 * 2;
    float* bias2 = (float*)w;                   w += 1024 * 4;
    int* cnt = (int*)w;                         w += (size_t)NNODES * RREL * 4;
    int* deg = (int*)w;                         w += (size_t)NNODES * 4;
    int* startv = (int*)w;                      w += (size_t)NNODES * 4;
    int* start2 = (int*)w;                      w += (size_t)NNODES * RREL * 4;
    int* cursor2 = (int*)w;                     w += (size_t)NNODES * RREL * 4;
    int* csr = (int*)w;                         w += (size_t)NEDGES * 4;
    float* sums = (float*)w;                    w += 1024;
    float* sumsq = (float*)w;                   w += 1024;
    size_t need = (size_t)(w - (char*)d_ws);
    if (ws_size < need) return;

    hipMemsetAsync(cnt, 0, (size_t)NNODES * RREL * 4, stream);
    hipMemsetAsync(sums, 0, 2048, stream);

    k_count<<<(NEDGES + 255) / 256, 256, 0, stream>>>(dstA, etype, cnt);
    k_deg<<<(NNODES + 255) / 256, 256, 0, stream>>>(cnt, deg);
    k_scan<<<1, 256, 0, stream>>>(deg, startv);
    k_sub<<<(NNODES + 255) / 256, 256, 0, stream>>>(cnt, startv, start2, cursor2);
    k_fill<<<(NEDGES + 255) / 256, 256, 0, stream>>>(srcA, dstA, etype, cursor2, csr);

    k_prep<<<(PR0 + PR1 + PR2 + PR3) / 256, 256, 0, stream>>>(x, Wrel, Wroot, Wq, Wk, Wv, Ws,
                                                              bq, bk, bv, bs, x_bf, BtAp, B2p, bias2);

    // S[d] = [mean_r(x) | x] (bf16)
    k_mean<<<(NNODES + 3) / 4, 256, 0, stream>>>(x_bf, csr, start2, cnt, S);

    // x1bf = bf16(S @ [W_0..W_7; W_root] + b1); 32x256 tiles, K=2304 (nks=72), 625 blocks
    {
        int nwg = 625;
        int q = nwg / 8, rr = nwg % 8;
        k_gemm10<5><<<nwg, 256, 0, stream>>>(S, BtAp, b1, x1bf, nullptr, NNODES, 2304, 72, 1, q, rr);
    }

    // [q|k|v -> QKVbf, skip -> out] = x1 @ [Wq|Wk|Wv|Wskip] + bias2; 32x256 tiles, 625x4 blocks
    {
        int nwg = 625 * 4;
        int q = nwg / 8, rr = nwg % 8;
        k_gemm10<3><<<nwg, 256, 0, stream>>>(x1bf, B2p, bias2, QKVbf, out, NNODES, 256, 8, 4, q, rr);
    }

    k_attn<<<(NNODES + 3) / 4, 256, 0, stream>>>(QKVbf, csr, start2, deg, out);

    k_bnstats<<<400, 256, 0, stream>>>(out, sums, sumsq);
    k_bnapply<<<(NNODES * 64 + 255) / 256, 256, 0, stream>>>((float4*)out, sums, sumsq, gamma, beta);
}